// Round 6
// baseline (294.035 us; speedup 1.0000x reference)
//
#include <hip/hip_runtime.h>
#include <cstdint>
#include <cstddef>

typedef float  f32x4  __attribute__((ext_vector_type(4)));
typedef short  bf16x8 __attribute__((ext_vector_type(8)));
typedef short  bf16x4 __attribute__((ext_vector_type(4)));

constexpr int Bc = 4, Lc = 1024, Dc = 1024, Kc = 8, Hc = 64, NHc = 512;
constexpr float SCALE = 0.125f;                       // 1/sqrt(64)
constexpr long long GSZ = 2LL * Bc * Kc * Lc * Lc;    // graphs elems (both layers)
constexpr long long OSZ = (long long)Bc * Lc * Dc;    // hidden elems per layer
constexpr int SROW = 1036;                            // S row stride (floats)

__device__ __forceinline__ unsigned short f2bf(float f) {
    unsigned u = __float_as_uint(f);
    u += 0x7fffu + ((u >> 16) & 1u);   // RNE
    return (unsigned short)(u >> 16);
}

// ---------------------------------------------------------------------------
// cast fp32 -> bf16, 8 elems/thread
// ---------------------------------------------------------------------------
__global__ __launch_bounds__(256)
void cast_bf16(const float* __restrict__ in, unsigned short* __restrict__ outp, int n)
{
    const int i = (blockIdx.x * 256 + threadIdx.x) * 8;
    if (i >= n) return;
    float4 a = *(const float4*)(in + i);
    float4 b = *(const float4*)(in + i + 4);
    bf16x8 v;
    v[0] = (short)f2bf(a.x); v[1] = (short)f2bf(a.y);
    v[2] = (short)f2bf(a.z); v[3] = (short)f2bf(a.w);
    v[4] = (short)f2bf(b.x); v[5] = (short)f2bf(b.y);
    v[6] = (short)f2bf(b.z); v[7] = (short)f2bf(b.w);
    *(bf16x8*)(outp + i) = v;
}

// ---------------------------------------------------------------------------
// cast + transpose: src fp32 [4][1024 s][1024 d] -> hidT bf16 [4][1024 d][1024 s]
// 64x64 tile via LDS.
// ---------------------------------------------------------------------------
__global__ __launch_bounds__(256)
void cast_tr(const float* __restrict__ src, unsigned short* __restrict__ hidT)
{
    __shared__ float Tl[64][68];
    const int b = blockIdx.z, s0 = blockIdx.x * 64, d0 = blockIdx.y * 64;
    const int t = threadIdx.x;
    {
        const int r = t >> 4, c = (t & 15) * 4;
        #pragma unroll
        for (int i = 0; i < 4; ++i)
            *(float4*)&Tl[r + 16 * i][c] =
                *(const float4*)&src[((size_t)(b * Lc + s0 + r + 16 * i)) * Dc + d0 + c];
    }
    __syncthreads();
    {
        const int d = t >> 2, sc = (t & 3) * 16;
        bf16x8 v0, v1;
        #pragma unroll
        for (int j = 0; j < 8; ++j) v0[j] = (short)f2bf(Tl[sc + j][d]);
        #pragma unroll
        for (int j = 0; j < 8; ++j) v1[j] = (short)f2bf(Tl[sc + 8 + j][d]);
        unsigned short* dp = hidT + ((size_t)(b * Dc + d0 + d)) * Lc + s0 + sc;
        *(bf16x8*)dp       = v0;
        *(bf16x8*)(dp + 8) = v1;
    }
}

// ---------------------------------------------------------------------------
// K0: W [1024 k][512 n] fp32 -> Wt [512 n][1024 k] bf16, parked in d_out att
// region (overwritten later by attn_fused). z: layer*2 + (0=q,1=k).
// ---------------------------------------------------------------------------
__global__ __launch_bounds__(256)
void wtrans(const float* __restrict__ Wq, const float* __restrict__ Wk,
            float* __restrict__ outbase)
{
    __shared__ float Tl[64][68];
    const int z = blockIdx.z, layer = z >> 1, m = z & 1;
    const float* src = (m ? Wk : Wq) + (size_t)layer * Dc * NHc;
    unsigned short* dst = (unsigned short*)(outbase + (size_t)layer * (GSZ / 2))
                          + (size_t)m * NHc * Dc;
    const int k0 = blockIdx.x * 64, n0 = blockIdx.y * 64;
    const int t = threadIdx.x;
    {
        const int r0 = t >> 4, c0 = (t & 15) * 4;
        #pragma unroll
        for (int i = 0; i < 4; ++i)
            *(float4*)&Tl[r0 + 16 * i][c0] =
                *(const float4*)&src[(size_t)(k0 + r0 + 16 * i) * NHc + n0 + c0];
    }
    __syncthreads();
    {
        const int nn = t >> 2, ks = (t & 3) * 16;
        bf16x8 v0, v1;
        #pragma unroll
        for (int j = 0; j < 8; ++j) v0[j] = (short)f2bf(Tl[ks + j][nn]);
        #pragma unroll
        for (int j = 0; j < 8; ++j) v1[j] = (short)f2bf(Tl[ks + 8 + j][nn]);
        unsigned short* dp = dst + (size_t)(n0 + nn) * Dc + k0 + ks;
        *(bf16x8*)dp       = v0;
        *(bf16x8*)(dp + 8) = v1;
    }
}

// ---------------------------------------------------------------------------
// K1: q = relu(hid@Wq+bq) bf16, k = relu(hid@Wk+bk) bf16.  MFMA 16x16x32.
// ---------------------------------------------------------------------------
__global__ __launch_bounds__(512)
void qk_gemm(const unsigned short* __restrict__ hidb,
             const unsigned short* __restrict__ Wtq, const unsigned short* __restrict__ Wtk,
             const float* __restrict__ bq, const float* __restrict__ bk,
             unsigned short* __restrict__ qbuf, unsigned short* __restrict__ kbuf)
{
    const unsigned short* Wt = blockIdx.z ? Wtk : Wtq;
    const float* bi = blockIdx.z ? bk : bq;
    unsigned short* C = blockIdx.z ? kbuf : qbuf;
    const int m0 = blockIdx.x * 128, n0 = blockIdx.y * 128;
    const int t = threadIdx.x, lane = t & 63, w = t >> 6;
    const int lr = lane & 15, lg = lane >> 4;
    const int wm = m0 + (w >> 2) * 64;
    const int wn = n0 + (w & 3) * 32;

    f32x4 acc[4][2] = {};
    const unsigned short* Ap = hidb + (size_t)(wm + lr) * Dc + lg * 8;
    const unsigned short* Bp = Wt + (size_t)(wn + lr) * Dc + lg * 8;

    for (int k0 = 0; k0 < Dc; k0 += 32) {
        bf16x8 a[4], bfr[2];
        #pragma unroll
        for (int mi = 0; mi < 4; ++mi)
            a[mi] = *(const bf16x8*)(Ap + (size_t)mi * 16 * Dc + k0);
        #pragma unroll
        for (int ni = 0; ni < 2; ++ni)
            bfr[ni] = *(const bf16x8*)(Bp + (size_t)ni * 16 * Dc + k0);
        #pragma unroll
        for (int mi = 0; mi < 4; ++mi)
            #pragma unroll
            for (int ni = 0; ni < 2; ++ni)
                acc[mi][ni] = __builtin_amdgcn_mfma_f32_16x16x32_bf16(a[mi], bfr[ni], acc[mi][ni], 0, 0, 0);
    }

    #pragma unroll
    for (int ni = 0; ni < 2; ++ni) {
        const int gc = wn + ni * 16 + lr;
        const float bv = bi[gc];
        #pragma unroll
        for (int mi = 0; mi < 4; ++mi)
            #pragma unroll
            for (int r = 0; r < 4; ++r) {
                const int row = wm + mi * 16 + lg * 4 + r;
                float v = fmaxf(acc[mi][ni][r] + bv, 0.0f);
                C[(size_t)row * NHc + gc] = f2bf(v);
            }
    }
}

// ---------------------------------------------------------------------------
// K2 (fused): scores -> softmax (writes att fp32 + P bf16 into LDS) -> PV ->
// residual, per 16 q-rows.  P stored bf16 in-place over the score strip with
// XOR-swizzled 8-elem groups; V read from pre-transposed hidT (b128 loads).
// ---------------------------------------------------------------------------
__global__ __launch_bounds__(512)
void attn_fused(const unsigned short* __restrict__ qbuf,
                const unsigned short* __restrict__ kbuf,
                const unsigned short* __restrict__ hidT,
                const float* __restrict__ res,
                float* __restrict__ att, float* __restrict__ outp)
{
    __shared__ float S[16][SROW];
    const int qt = blockIdx.x, kh = blockIdx.y, b = blockIdx.z;
    const int q0 = qt * 16;
    const int t = threadIdx.x, lane = t & 63, w = t >> 6;
    const int lr = lane & 15, lg = lane >> 4;

    // ---- phase 1: scaled scores into S (causal chunks only) ----
    bf16x8 aq[2];
    #pragma unroll
    for (int ks = 0; ks < 2; ++ks)
        aq[ks] = *(const bf16x8*)(qbuf + (size_t)(b * Lc + q0 + lr) * NHc + kh * Hc + ks * 32 + lg * 8);

    const int ccount = (q0 + 16 + 63) >> 6;
    for (int c = w; c < ccount; c += 8) {
        f32x4 acc[4] = {};
        #pragma unroll
        for (int ks = 0; ks < 2; ++ks)
            #pragma unroll
            for (int ni = 0; ni < 4; ++ni) {
                const int s = c * 64 + ni * 16 + lr;
                bf16x8 bfr = *(const bf16x8*)(kbuf + (size_t)(b * Lc + s) * NHc + kh * Hc + ks * 32 + lg * 8);
                acc[ni] = __builtin_amdgcn_mfma_f32_16x16x32_bf16(aq[ks], bfr, acc[ni], 0, 0, 0);
            }
        #pragma unroll
        for (int ni = 0; ni < 4; ++ni)
            #pragma unroll
            for (int r = 0; r < 4; ++r)
                S[lg * 4 + r][c * 64 + ni * 16 + lr] = acc[ni][r] * SCALE;
    }
    __syncthreads();

    // ---- phase 2: softmax; write att fp32 to global and P bf16 into LDS
    //      (in-place over this row's own storage; reads complete first) ----
    unsigned short* PbBase = (unsigned short*)&S[0][0];
    #pragma unroll
    for (int i = 0; i < 2; ++i) {
        const int row = w * 2 + i, qrow = q0 + row;
        unsigned short* PbRow = PbBase + (size_t)row * (2 * SROW);
        float* orow = att + ((size_t)(b * Kc + kh) * Lc + qrow) * Lc;
        if (qrow == 0) {
            const float u = 1.0f / 1024.0f;
            const unsigned short ub = f2bf(u);
            bf16x4 pv = { (short)ub, (short)ub, (short)ub, (short)ub };
            #pragma unroll
            for (int tt = 0; tt < 4; ++tt) {
                const int col = lane * 4 + tt * 256;
                float4 o = { u, u, u, u };
                *(float4*)(orow + col) = o;
                const int grp = col >> 3;          // row==0 -> no swizzle
                *(bf16x4*)(PbRow + grp * 8 + (lane & 1) * 4) = pv;
            }
            continue;
        }
        float p[16];
        float mx = -3.0e38f;
        #pragma unroll
        for (int tt = 0; tt < 4; ++tt) {
            const int col = lane * 4 + tt * 256;
            float4 x = *(const float4*)&S[row][col];
            p[tt*4+0] = x.x; p[tt*4+1] = x.y; p[tt*4+2] = x.z; p[tt*4+3] = x.w;
            if (col + 0 < qrow) mx = fmaxf(mx, x.x);
            if (col + 1 < qrow) mx = fmaxf(mx, x.y);
            if (col + 2 < qrow) mx = fmaxf(mx, x.z);
            if (col + 3 < qrow) mx = fmaxf(mx, x.w);
        }
        #pragma unroll
        for (int off = 1; off < 64; off <<= 1) mx = fmaxf(mx, __shfl_xor(mx, off));
        float sum = 0.0f;
        #pragma unroll
        for (int tt = 0; tt < 4; ++tt)
            #pragma unroll
            for (int j = 0; j < 4; ++j) {
                const int col = lane * 4 + tt * 256 + j;
                const float e = (col < qrow) ? __expf(p[tt*4+j] - mx) : 0.0f;
                p[tt*4+j] = e; sum += e;
            }
        #pragma unroll
        for (int off = 1; off < 64; off <<= 1) sum += __shfl_xor(sum, off);
        const float inv = 1.0f / sum;
        #pragma unroll
        for (int tt = 0; tt < 4; ++tt) {
            const int col = lane * 4 + tt * 256;
            float4 o = { p[tt*4+0]*inv, p[tt*4+1]*inv, p[tt*4+2]*inv, p[tt*4+3]*inv };
            *(float4*)(orow + col) = o;
            const int grp  = col >> 3;
            const int grpS = grp ^ (row & 7);
            bf16x4 pv;
            pv[0] = (short)f2bf(o.x); pv[1] = (short)f2bf(o.y);
            pv[2] = (short)f2bf(o.z); pv[3] = (short)f2bf(o.w);
            *(bf16x4*)(PbRow + grpS * 8 + (lane & 1) * 4) = pv;
        }
    }
    __syncthreads();

    // ---- phase 3: PV (+residual).  Wave w owns d-cols [w*16, w*16+16). ----
    const int stiles = (qt == 0) ? 16 : ccount;
    f32x4 acc = {};
    const int dcol = kh * 128 + w * 16 + lr;
    const unsigned short* vT = hidT + ((size_t)(b * Dc + dcol)) * Lc;
    const unsigned short* PbMy = PbBase + (size_t)lr * (2 * SROW);
    const int r7 = lr & 7;
    for (int ti = 0; ti < stiles; ++ti) {
        const int s0 = ti * 64;
        #pragma unroll
        for (int ks = 0; ks < 2; ++ks) {
            const int grp  = (s0 >> 3) + ks * 4 + lg;
            const int grpS = grp ^ r7;
            bf16x8 a  = *(const bf16x8*)(PbMy + grpS * 8);
            bf16x8 bb = *(const bf16x8*)(vT + s0 + ks * 32 + lg * 8);
            acc = __builtin_amdgcn_mfma_f32_16x16x32_bf16(a, bb, acc, 0, 0, 0);
        }
    }
    #pragma unroll
    for (int r = 0; r < 4; ++r) {
        const size_t idx = (size_t)(b * Lc + q0 + lg * 4 + r) * Dc + dcol;
        outp[idx] = res[idx] + acc[r];
    }
}

// ---------------------------------------------------------------------------
extern "C" void kernel_launch(void* const* d_in, const int* in_sizes, int n_in,
                              void* d_out, int out_size, void* d_ws, size_t ws_size,
                              hipStream_t stream)
{
    const float* x  = (const float*)d_in[0];
    const float* Wq = (const float*)d_in[1];
    const float* bq = (const float*)d_in[2];
    const float* Wk = (const float*)d_in[3];
    const float* bk = (const float*)d_in[4];
    float* out = (float*)d_out;

    unsigned short* hidb = (unsigned short*)d_ws;              // [4096][1024] bf16 (8 MB)
    unsigned short* hidT = hidb + (size_t)Bc * Lc * Dc;        // [4][1024][1024] bf16 (8 MB)
    unsigned short* qb   = hidT + (size_t)Bc * Dc * Lc;        // [4096][512]  bf16 (4 MB)
    unsigned short* kb   = qb   + (size_t)Bc * Lc * NHc;       // [4096][512]  bf16 (4 MB)

    const int nhid = Bc * Lc * Dc;   // 4194304

    wtrans<<<dim3(16, 8, 4), 256, 0, stream>>>(Wq, Wk, out);

    for (int l = 0; l < 2; ++l) {
        float* attL = out + (size_t)l * (GSZ / 2);
        float* outL = out + GSZ + (size_t)l * OSZ;
        const float* resL = l ? (out + GSZ) : x;
        const float* srcL = l ? (out + GSZ) : x;   // fp32 hidden entering layer l
        const unsigned short* WtL = (const unsigned short*)attL;

        cast_bf16<<<nhid / 8 / 256, 256, 0, stream>>>(srcL, hidb, nhid);
        cast_tr<<<dim3(16, 16, 4), 256, 0, stream>>>(srcL, hidT);

        qk_gemm<<<dim3(32, 4, 2), 512, 0, stream>>>(
            hidb, WtL, WtL + (size_t)NHc * Dc, bq + l * NHc, bk + l * NHc, qb, kb);

        attn_fused<<<dim3(64, 8, 4), 512, 0, stream>>>(qb, kb, hidT, resL, attL, outL);
    }
}

// Round 8
// 261.669 us; speedup vs baseline: 1.1237x; 1.1237x over previous
//
#include <hip/hip_runtime.h>
#include <cstdint>
#include <cstddef>

typedef float  f32x4  __attribute__((ext_vector_type(4)));
typedef short  bf16x8 __attribute__((ext_vector_type(8)));

constexpr int Bc = 4, Lc = 1024, Dc = 1024, Kc = 8, Hc = 64, NHc = 512;
constexpr float SCALE = 0.125f;                       // 1/sqrt(64)
constexpr long long GSZ = 2LL * Bc * Kc * Lc * Lc;    // graphs elems (both layers)
constexpr long long OSZ = (long long)Bc * Lc * Dc;    // hidden elems per layer
constexpr int QB = 32;                                // q-rows per attn block
constexpr int SROW = 1036;                            // S row stride (floats)

__device__ __forceinline__ unsigned short f2bf(float f) {
    unsigned u = __float_as_uint(f);
    u += 0x7fffu + ((u >> 16) & 1u);   // RNE
    return (unsigned short)(u >> 16);
}

// ---------------------------------------------------------------------------
// cast fp32 -> bf16, 8 elems/thread
// ---------------------------------------------------------------------------
__global__ __launch_bounds__(256)
void cast_bf16(const float* __restrict__ in, unsigned short* __restrict__ outp, int n)
{
    const int i = (blockIdx.x * 256 + threadIdx.x) * 8;
    if (i >= n) return;
    float4 a = *(const float4*)(in + i);
    float4 b = *(const float4*)(in + i + 4);
    bf16x8 v;
    v[0] = (short)f2bf(a.x); v[1] = (short)f2bf(a.y);
    v[2] = (short)f2bf(a.z); v[3] = (short)f2bf(a.w);
    v[4] = (short)f2bf(b.x); v[5] = (short)f2bf(b.y);
    v[6] = (short)f2bf(b.z); v[7] = (short)f2bf(b.w);
    *(bf16x8*)(outp + i) = v;
}

// ---------------------------------------------------------------------------
// K0: W [1024 k][512 n] fp32 -> Wt [512 n][1024 k] bf16, parked in d_out att
// region (overwritten later by attn_fused). z: layer*2 + (0=q,1=k).
// ---------------------------------------------------------------------------
__global__ __launch_bounds__(256)
void wtrans(const float* __restrict__ Wq, const float* __restrict__ Wk,
            float* __restrict__ outbase)
{
    __shared__ float Tl[64][68];
    const int z = blockIdx.z, layer = z >> 1, m = z & 1;
    const float* src = (m ? Wk : Wq) + (size_t)layer * Dc * NHc;
    unsigned short* dst = (unsigned short*)(outbase + (size_t)layer * (GSZ / 2))
                          + (size_t)m * NHc * Dc;
    const int k0 = blockIdx.x * 64, n0 = blockIdx.y * 64;
    const int t = threadIdx.x;
    {
        const int r0 = t >> 4, c0 = (t & 15) * 4;
        #pragma unroll
        for (int i = 0; i < 4; ++i)
            *(float4*)&Tl[r0 + 16 * i][c0] =
                *(const float4*)&src[(size_t)(k0 + r0 + 16 * i) * NHc + n0 + c0];
    }
    __syncthreads();
    {
        const int nn = t >> 2, ks = (t & 3) * 16;
        bf16x8 v0, v1;
        #pragma unroll
        for (int j = 0; j < 8; ++j) v0[j] = (short)f2bf(Tl[ks + j][nn]);
        #pragma unroll
        for (int j = 0; j < 8; ++j) v1[j] = (short)f2bf(Tl[ks + 8 + j][nn]);
        unsigned short* dp = dst + (size_t)(n0 + nn) * Dc + k0 + ks;
        *(bf16x8*)dp       = v0;
        *(bf16x8*)(dp + 8) = v1;
    }
}

// ---------------------------------------------------------------------------
// K1: q = relu(hid@Wq+bq) bf16, k = relu(hid@Wk+bk) bf16.  MFMA 16x16x32.
// ---------------------------------------------------------------------------
__global__ __launch_bounds__(512)
void qk_gemm(const unsigned short* __restrict__ hidb,
             const unsigned short* __restrict__ Wtq, const unsigned short* __restrict__ Wtk,
             const float* __restrict__ bq, const float* __restrict__ bk,
             unsigned short* __restrict__ qbuf, unsigned short* __restrict__ kbuf)
{
    const unsigned short* Wt = blockIdx.z ? Wtk : Wtq;
    const float* bi = blockIdx.z ? bk : bq;
    unsigned short* C = blockIdx.z ? kbuf : qbuf;
    const int m0 = blockIdx.x * 128, n0 = blockIdx.y * 128;
    const int t = threadIdx.x, lane = t & 63, w = t >> 6;
    const int lr = lane & 15, lg = lane >> 4;
    const int wm = m0 + (w >> 2) * 64;
    const int wn = n0 + (w & 3) * 32;

    f32x4 acc[4][2] = {};
    const unsigned short* Ap = hidb + (size_t)(wm + lr) * Dc + lg * 8;
    const unsigned short* Bp = Wt + (size_t)(wn + lr) * Dc + lg * 8;

    for (int k0 = 0; k0 < Dc; k0 += 32) {
        bf16x8 a[4], bfr[2];
        #pragma unroll
        for (int mi = 0; mi < 4; ++mi)
            a[mi] = *(const bf16x8*)(Ap + (size_t)mi * 16 * Dc + k0);
        #pragma unroll
        for (int ni = 0; ni < 2; ++ni)
            bfr[ni] = *(const bf16x8*)(Bp + (size_t)ni * 16 * Dc + k0);
        #pragma unroll
        for (int mi = 0; mi < 4; ++mi)
            #pragma unroll
            for (int ni = 0; ni < 2; ++ni)
                acc[mi][ni] = __builtin_amdgcn_mfma_f32_16x16x32_bf16(a[mi], bfr[ni], acc[mi][ni], 0, 0, 0);
    }

    #pragma unroll
    for (int ni = 0; ni < 2; ++ni) {
        const int gc = wn + ni * 16 + lr;
        const float bv = bi[gc];
        #pragma unroll
        for (int mi = 0; mi < 4; ++mi)
            #pragma unroll
            for (int r = 0; r < 4; ++r) {
                const int row = wm + mi * 16 + lg * 4 + r;
                float v = fmaxf(acc[mi][ni][r] + bv, 0.0f);
                C[(size_t)row * NHc + gc] = f2bf(v);
            }
    }
}

// ---------------------------------------------------------------------------
// K2 (fused): scores -> softmax -> att write -> PV -> residual, 32 q-rows per
// block.  1-D grid, id%8 == head so all q-tiles of one (b,head) share an XCD
// (L2-resident K/Q/V).  Epilogue optionally emits bf16 hidden for next layer.
// Causal: valid iff s < q.  Row q==0 -> uniform 1/1024 (matches jax ref).
// ---------------------------------------------------------------------------
__global__ __launch_bounds__(512)
void attn_fused(const unsigned short* __restrict__ qbuf,
                const unsigned short* __restrict__ kbuf,
                const unsigned short* __restrict__ hidb,
                const float* __restrict__ res,
                float* __restrict__ att, float* __restrict__ outp,
                unsigned short* __restrict__ hidnext)
{
    __shared__ float S[QB][SROW];
    const int id = blockIdx.x;
    const int kh = id & 7, qt = (id >> 3) & 31, b = id >> 8;
    const int q0 = qt * QB;
    const int t = threadIdx.x, lane = t & 63, w = t >> 6;
    const int lr = lane & 15, lg = lane >> 4;

    // ---- phase 1: scaled scores into S (causal chunks only) ----
    bf16x8 aq[2][2];   // [mf][ks]
    #pragma unroll
    for (int mf = 0; mf < 2; ++mf)
        #pragma unroll
        for (int ks = 0; ks < 2; ++ks)
            aq[mf][ks] = *(const bf16x8*)(qbuf + (size_t)(b * Lc + q0 + mf * 16 + lr) * NHc
                                          + kh * Hc + ks * 32 + lg * 8);

    const int ccount = (q0 + QB + 63) >> 6;
    for (int c = w; c < ccount; c += 8) {
        f32x4 acc[2][4] = {};
        #pragma unroll
        for (int ks = 0; ks < 2; ++ks)
            #pragma unroll
            for (int ni = 0; ni < 4; ++ni) {
                const int s = c * 64 + ni * 16 + lr;
                bf16x8 bfr = *(const bf16x8*)(kbuf + (size_t)(b * Lc + s) * NHc
                                              + kh * Hc + ks * 32 + lg * 8);
                #pragma unroll
                for (int mf = 0; mf < 2; ++mf)
                    acc[mf][ni] = __builtin_amdgcn_mfma_f32_16x16x32_bf16(aq[mf][ks], bfr, acc[mf][ni], 0, 0, 0);
            }
        #pragma unroll
        for (int mf = 0; mf < 2; ++mf)
            #pragma unroll
            for (int ni = 0; ni < 4; ++ni)
                #pragma unroll
                for (int r = 0; r < 4; ++r)
                    S[mf * 16 + lg * 4 + r][c * 64 + ni * 16 + lr] = acc[mf][ni][r] * SCALE;
    }
    __syncthreads();

    // ---- phase 2: softmax per row (4 rows per wave); write att fp32 to
    //      global and normalized P back into S (full row incl. zeros) ----
    #pragma unroll
    for (int i = 0; i < 4; ++i) {
        const int row = w * 4 + i, qrow = q0 + row;
        float* orow = att + ((size_t)(b * Kc + kh) * Lc + qrow) * Lc;
        if (qrow == 0) {
            const float u = 1.0f / 1024.0f;
            #pragma unroll
            for (int tt = 0; tt < 4; ++tt) {
                const int col = lane * 4 + tt * 256;
                float4 o = { u, u, u, u };
                *(float4*)&S[row][col] = o;
                *(float4*)(orow + col) = o;
            }
            continue;
        }
        float p[16];
        float mx = -3.0e38f;
        #pragma unroll
        for (int tt = 0; tt < 4; ++tt) {
            const int col = lane * 4 + tt * 256;
            float4 x = *(const float4*)&S[row][col];
            p[tt*4+0] = x.x; p[tt*4+1] = x.y; p[tt*4+2] = x.z; p[tt*4+3] = x.w;
            if (col + 0 < qrow) mx = fmaxf(mx, x.x);
            if (col + 1 < qrow) mx = fmaxf(mx, x.y);
            if (col + 2 < qrow) mx = fmaxf(mx, x.z);
            if (col + 3 < qrow) mx = fmaxf(mx, x.w);
        }
        #pragma unroll
        for (int off = 1; off < 64; off <<= 1) mx = fmaxf(mx, __shfl_xor(mx, off));
        float sum = 0.0f;
        #pragma unroll
        for (int tt = 0; tt < 4; ++tt)
            #pragma unroll
            for (int j = 0; j < 4; ++j) {
                const int col = lane * 4 + tt * 256 + j;
                const float e = (col < qrow) ? __expf(p[tt*4+j] - mx) : 0.0f;
                p[tt*4+j] = e; sum += e;
            }
        #pragma unroll
        for (int off = 1; off < 64; off <<= 1) sum += __shfl_xor(sum, off);
        const float inv = 1.0f / sum;
        #pragma unroll
        for (int tt = 0; tt < 4; ++tt) {
            const int col = lane * 4 + tt * 256;
            float4 o = { p[tt*4+0]*inv, p[tt*4+1]*inv, p[tt*4+2]*inv, p[tt*4+3]*inv };
            *(float4*)&S[row][col] = o;
            *(float4*)(orow + col) = o;
        }
    }
    __syncthreads();

    // ---- phase 3: PV (+residual).  Wave w owns d-cols [w*16, w*16+16) for
    //      all 32 q-rows (2 MFMA row-fragments). ----
    const int stiles = (qt == 0) ? 16 : ccount;   // row 0 is a full uniform row
    f32x4 acc3[2] = {};
    const int dcol = kh * 128 + w * 16 + lr;
    for (int ti = 0; ti < stiles; ++ti) {
        const int s0 = ti * 64;
        #pragma unroll
        for (int ks = 0; ks < 2; ++ks) {
            bf16x8 bb;
            const unsigned short* vp = hidb + (size_t)(b * Lc + s0 + ks * 32 + lg * 8) * Dc + dcol;
            #pragma unroll
            for (int j = 0; j < 8; ++j) bb[j] = (short)vp[(size_t)j * Dc];
            #pragma unroll
            for (int mf = 0; mf < 2; ++mf) {
                const float* ap = &S[mf * 16 + lr][s0 + ks * 32 + lg * 8];
                float4 x0 = *(const float4*)ap;
                float4 x1 = *(const float4*)(ap + 4);
                bf16x8 a;
                a[0] = (short)f2bf(x0.x); a[1] = (short)f2bf(x0.y);
                a[2] = (short)f2bf(x0.z); a[3] = (short)f2bf(x0.w);
                a[4] = (short)f2bf(x1.x); a[5] = (short)f2bf(x1.y);
                a[6] = (short)f2bf(x1.z); a[7] = (short)f2bf(x1.w);
                acc3[mf] = __builtin_amdgcn_mfma_f32_16x16x32_bf16(a, bb, acc3[mf], 0, 0, 0);
            }
        }
    }
    #pragma unroll
    for (int mf = 0; mf < 2; ++mf)
        #pragma unroll
        for (int r = 0; r < 4; ++r) {
            const size_t idx = (size_t)(b * Lc + q0 + mf * 16 + lg * 4 + r) * Dc + dcol;
            const float v = res[idx] + acc3[mf][r];
            outp[idx] = v;
            if (hidnext) hidnext[idx] = f2bf(v);
        }
}

// ---------------------------------------------------------------------------
extern "C" void kernel_launch(void* const* d_in, const int* in_sizes, int n_in,
                              void* d_out, int out_size, void* d_ws, size_t ws_size,
                              hipStream_t stream)
{
    const float* x  = (const float*)d_in[0];
    const float* Wq = (const float*)d_in[1];
    const float* bq = (const float*)d_in[2];
    const float* Wk = (const float*)d_in[3];
    const float* bk = (const float*)d_in[4];
    float* out = (float*)d_out;

    unsigned short* hidbA = (unsigned short*)d_ws;             // [4096][1024] bf16 (8 MB)
    unsigned short* hidbB = hidbA + (size_t)Bc * Lc * Dc;      // [4096][1024] bf16 (8 MB)
    unsigned short* qb    = hidbB + (size_t)Bc * Lc * Dc;      // [4096][512]  bf16 (4 MB)
    unsigned short* kb    = qb    + (size_t)Bc * Lc * NHc;     // [4096][512]  bf16 (4 MB)

    const int nhid = Bc * Lc * Dc;   // 4194304

    cast_bf16<<<nhid / 8 / 256, 256, 0, stream>>>(x, hidbA, nhid);
    wtrans<<<dim3(16, 8, 4), 256, 0, stream>>>(Wq, Wk, out);

    for (int l = 0; l < 2; ++l) {
        float* attL = out + (size_t)l * (GSZ / 2);
        float* outL = out + GSZ + (size_t)l * OSZ;
        const float* resL = l ? (out + GSZ) : x;
        const unsigned short* hidL = l ? hidbB : hidbA;
        const unsigned short* WtL = (const unsigned short*)attL;

        qk_gemm<<<dim3(32, 4, 2), 512, 0, stream>>>(
            hidL, WtL, WtL + (size_t)NHc * Dc, bq + l * NHc, bk + l * NHc, qb, kb);

        attn_fused<<<Bc * 32 * Kc, 512, 0, stream>>>(
            qb, kb, hidL, resL, attL, outL, l == 0 ? hidbB : (unsigned short*)nullptr);
    }
}

// Round 9
// 193.705 us; speedup vs baseline: 1.5180x; 1.3509x over previous
//
#include <hip/hip_runtime.h>
#include <cstdint>
#include <cstddef>

typedef float  f32x4  __attribute__((ext_vector_type(4)));
typedef short  bf16x8 __attribute__((ext_vector_type(8)));

constexpr int Bc = 4, Lc = 1024, Dc = 1024, Kc = 8, Hc = 64, NHc = 512;
constexpr float SCALE = 0.125f;                       // 1/sqrt(64)
constexpr long long GSZ = 2LL * Bc * Kc * Lc * Lc;    // graphs elems (both layers)
constexpr long long OSZ = (long long)Bc * Lc * Dc;    // hidden elems per layer
constexpr int QB = 16;                                // q-rows per attn block

__device__ __forceinline__ unsigned short f2bf(float f) {
    unsigned u = __float_as_uint(f);
    u += 0x7fffu + ((u >> 16) & 1u);   // RNE
    return (unsigned short)(u >> 16);
}
__device__ __forceinline__ float bf2f(unsigned short s) {
    return __uint_as_float((unsigned)s << 16);
}

// ---------------------------------------------------------------------------
// cast fp32 -> bf16, 8 elems/thread
// ---------------------------------------------------------------------------
__global__ __launch_bounds__(256)
void cast_bf16(const float* __restrict__ in, unsigned short* __restrict__ outp, int n)
{
    const int i = (blockIdx.x * 256 + threadIdx.x) * 8;
    if (i >= n) return;
    float4 a = *(const float4*)(in + i);
    float4 b = *(const float4*)(in + i + 4);
    bf16x8 v;
    v[0] = (short)f2bf(a.x); v[1] = (short)f2bf(a.y);
    v[2] = (short)f2bf(a.z); v[3] = (short)f2bf(a.w);
    v[4] = (short)f2bf(b.x); v[5] = (short)f2bf(b.y);
    v[6] = (short)f2bf(b.z); v[7] = (short)f2bf(b.w);
    *(bf16x8*)(outp + i) = v;
}

// ---------------------------------------------------------------------------
// K0: W [1024 k][512 n] fp32 -> Wt [512 n][1024 k] bf16, parked in d_out att
// region (overwritten later by attn_fused). z: layer*2 + (0=q,1=k).
// ---------------------------------------------------------------------------
__global__ __launch_bounds__(256)
void wtrans(const float* __restrict__ Wq, const float* __restrict__ Wk,
            float* __restrict__ outbase)
{
    __shared__ float Tl[64][68];
    const int z = blockIdx.z, layer = z >> 1, m = z & 1;
    const float* src = (m ? Wk : Wq) + (size_t)layer * Dc * NHc;
    unsigned short* dst = (unsigned short*)(outbase + (size_t)layer * (GSZ / 2))
                          + (size_t)m * NHc * Dc;
    const int k0 = blockIdx.x * 64, n0 = blockIdx.y * 64;
    const int t = threadIdx.x;
    {
        const int r0 = t >> 4, c0 = (t & 15) * 4;
        #pragma unroll
        for (int i = 0; i < 4; ++i)
            *(float4*)&Tl[r0 + 16 * i][c0] =
                *(const float4*)&src[(size_t)(k0 + r0 + 16 * i) * NHc + n0 + c0];
    }
    __syncthreads();
    {
        const int nn = t >> 2, ks = (t & 3) * 16;
        bf16x8 v0, v1;
        #pragma unroll
        for (int j = 0; j < 8; ++j) v0[j] = (short)f2bf(Tl[ks + j][nn]);
        #pragma unroll
        for (int j = 0; j < 8; ++j) v1[j] = (short)f2bf(Tl[ks + 8 + j][nn]);
        unsigned short* dp = dst + (size_t)(n0 + nn) * Dc + k0 + ks;
        *(bf16x8*)dp       = v0;
        *(bf16x8*)(dp + 8) = v1;
    }
}

// ---------------------------------------------------------------------------
// K1: q/k projection GEMM, LDS-staged (coalesced global reads), double-buffered.
// Tile 128x128, BK=32, 512 thr = 8 waves, wave tile 64x32 (4x2 frags).
// ---------------------------------------------------------------------------
__global__ __launch_bounds__(512)
void qk_gemm(const unsigned short* __restrict__ hidb,
             const unsigned short* __restrict__ Wtq, const unsigned short* __restrict__ Wtk,
             const float* __restrict__ bq, const float* __restrict__ bk,
             unsigned short* __restrict__ qbuf, unsigned short* __restrict__ kbuf)
{
    __shared__ unsigned short As[2][128][40];
    __shared__ unsigned short Bs[2][128][40];

    const unsigned short* Wt = blockIdx.z ? Wtk : Wtq;
    const float* bi = blockIdx.z ? bk : bq;
    unsigned short* C = blockIdx.z ? kbuf : qbuf;
    const int m0 = blockIdx.x * 128, n0 = blockIdx.y * 128;
    const int t = threadIdx.x, lane = t & 63, w = t >> 6;
    const int lr = lane & 15, lg = lane >> 4;
    const int wmloc = (w >> 2) * 64, wnloc = (w & 3) * 32;

    // staging map: thread t -> row t>>2 (0..127), col (t&3)*8 (0..31)
    const int srow = t >> 2, scol = (t & 3) * 8;
    const unsigned short* Ag = hidb + (size_t)(m0 + srow) * Dc + scol;
    const unsigned short* Bg = Wt   + (size_t)(n0 + srow) * Dc + scol;

    f32x4 acc[4][2] = {};
    bf16x8 ra = *(const bf16x8*)Ag;
    bf16x8 rb = *(const bf16x8*)Bg;

    for (int it = 0; it < 32; ++it) {
        const int buf = it & 1;
        *(bf16x8*)&As[buf][srow][scol] = ra;
        *(bf16x8*)&Bs[buf][srow][scol] = rb;
        __syncthreads();
        if (it < 31) {
            ra = *(const bf16x8*)(Ag + (it + 1) * 32);
            rb = *(const bf16x8*)(Bg + (it + 1) * 32);
        }
        bf16x8 a[4], bfr[2];
        #pragma unroll
        for (int mi = 0; mi < 4; ++mi)
            a[mi] = *(const bf16x8*)&As[buf][wmloc + mi * 16 + lr][lg * 8];
        #pragma unroll
        for (int ni = 0; ni < 2; ++ni)
            bfr[ni] = *(const bf16x8*)&Bs[buf][wnloc + ni * 16 + lr][lg * 8];
        #pragma unroll
        for (int mi = 0; mi < 4; ++mi)
            #pragma unroll
            for (int ni = 0; ni < 2; ++ni)
                acc[mi][ni] = __builtin_amdgcn_mfma_f32_16x16x32_bf16(a[mi], bfr[ni], acc[mi][ni], 0, 0, 0);
    }

    #pragma unroll
    for (int ni = 0; ni < 2; ++ni) {
        const int gc = n0 + wnloc + ni * 16 + lr;
        const float bv = bi[gc];
        #pragma unroll
        for (int mi = 0; mi < 4; ++mi)
            #pragma unroll
            for (int r = 0; r < 4; ++r) {
                const int row = m0 + wmloc + mi * 16 + lg * 4 + r;
                float v = fmaxf(acc[mi][ni][r] + bv, 0.0f);
                C[(size_t)row * NHc + gc] = f2bf(v);
            }
    }
}

// ---------------------------------------------------------------------------
// K2 (fused): scores -> softmax -> att write -> PV -> residual, QB=16 q-rows
// per block, 512 thr = 8 waves.  Score strip in bf16 LDS; K and V tiles staged
// cooperatively (coalesced global) into a shared double buffer; all MFMA
// fragments come from LDS.  67 KB LDS -> 2 blocks/CU.
// Causal: valid iff s < q.  Row q==0 -> uniform 1/1024 (matches jax ref).
// ---------------------------------------------------------------------------
__global__ __launch_bounds__(512)
void attn_fused(const unsigned short* __restrict__ qbuf,
                const unsigned short* __restrict__ kbuf,
                const unsigned short* __restrict__ hidb,
                const float* __restrict__ res,
                float* __restrict__ att, float* __restrict__ outp,
                unsigned short* __restrict__ hidnext)
{
    __shared__ unsigned short Sb[QB][1040];     // bf16 score/P strip (33.3 KB)
    __shared__ unsigned short KV[2][64][132];   // K/V staging (33.8 KB)

    const int id = blockIdx.x;
    const int kh = id & 7, qt = (id >> 3) & 63, b = id >> 9;
    const int q0 = qt * QB;
    const int t = threadIdx.x, lane = t & 63, w = t >> 6;
    const int lr = lane & 15, lg = lane >> 4;

    // Q fragments (few scattered loads; negligible)
    bf16x8 aq[2];
    #pragma unroll
    for (int ks = 0; ks < 2; ++ks)
        aq[ks] = *(const bf16x8*)(qbuf + (size_t)(b * Lc + q0 + lr) * NHc + kh * Hc + ks * 32 + lg * 8);

    const int ccount = (q0 + QB + 63) >> 6;   // 64-col chunks needed (<=16)

    // ---- P1: scores -> Sb (bf16).  Stage 2 K-chunks, 8 waves split (chunk,ni).
    const int sh = t >> 8, srow = (t & 255) >> 2, scol = (t & 3) * 16;
    for (int cb = 0; cb < ccount; cb += 2) {
        const int cs = cb + sh;
        if (cs < ccount) {
            const unsigned short* kp = kbuf + (size_t)(b * Lc + cs * 64 + srow) * NHc + kh * Hc + scol;
            *(bf16x8*)&KV[sh][srow][scol]     = *(const bf16x8*)kp;
            *(bf16x8*)&KV[sh][srow][scol + 8] = *(const bf16x8*)(kp + 8);
        }
        __syncthreads();
        const int c = cb + (w >> 2);
        if (c < ccount) {
            const int ni = w & 3;
            f32x4 acc = {};
            #pragma unroll
            for (int ks = 0; ks < 2; ++ks) {
                bf16x8 bfr = *(const bf16x8*)&KV[w >> 2][ni * 16 + lr][ks * 32 + lg * 8];
                acc = __builtin_amdgcn_mfma_f32_16x16x32_bf16(aq[ks], bfr, acc, 0, 0, 0);
            }
            #pragma unroll
            for (int r = 0; r < 4; ++r)
                Sb[lg * 4 + r][c * 64 + ni * 16 + lr] = f2bf(acc[r] * SCALE);
        }
        __syncthreads();
    }

    // ---- P2: softmax, 2 rows per wave.  fp32 att to global; bf16 P to Sb. ----
    #pragma unroll
    for (int i = 0; i < 2; ++i) {
        const int row = w * 2 + i, qrow = q0 + row;
        float* orow = att + ((size_t)(b * Kc + kh) * Lc + qrow) * Lc;
        if (qrow == 0) {
            const float u = 1.0f / 1024.0f;
            const short ub = (short)f2bf(u);
            bf16x8 pv8;
            #pragma unroll
            for (int j = 0; j < 8; ++j) pv8[j] = ub;
            #pragma unroll
            for (int tt = 0; tt < 2; ++tt) {
                const int col = lane * 8 + tt * 512;
                float4 o = { u, u, u, u };
                *(float4*)(orow + col) = o;
                *(float4*)(orow + col + 4) = o;
                *(bf16x8*)&Sb[row][col] = pv8;
            }
            continue;
        }
        float p[16];
        float mx = -3.0e38f;
        #pragma unroll
        for (int tt = 0; tt < 2; ++tt) {
            const int col = lane * 8 + tt * 512;
            bf16x8 v = *(const bf16x8*)&Sb[row][col];
            #pragma unroll
            for (int j = 0; j < 8; ++j) {
                const float f = bf2f((unsigned short)v[j]);
                p[tt * 8 + j] = f;
                if (col + j < qrow) mx = fmaxf(mx, f);
            }
        }
        #pragma unroll
        for (int off = 1; off < 64; off <<= 1) mx = fmaxf(mx, __shfl_xor(mx, off));
        float sum = 0.0f;
        #pragma unroll
        for (int tt = 0; tt < 2; ++tt)
            #pragma unroll
            for (int j = 0; j < 8; ++j) {
                const int col = lane * 8 + tt * 512 + j;
                const float e = (col < qrow) ? __expf(p[tt * 8 + j] - mx) : 0.0f;
                p[tt * 8 + j] = e; sum += e;
            }
        #pragma unroll
        for (int off = 1; off < 64; off <<= 1) sum += __shfl_xor(sum, off);
        const float inv = 1.0f / sum;
        #pragma unroll
        for (int tt = 0; tt < 2; ++tt) {
            const int col = lane * 8 + tt * 512;
            float4 o0 = { p[tt*8+0]*inv, p[tt*8+1]*inv, p[tt*8+2]*inv, p[tt*8+3]*inv };
            float4 o1 = { p[tt*8+4]*inv, p[tt*8+5]*inv, p[tt*8+6]*inv, p[tt*8+7]*inv };
            *(float4*)(orow + col) = o0;
            *(float4*)(orow + col + 4) = o1;
            bf16x8 pb;
            #pragma unroll
            for (int j = 0; j < 8; ++j) pb[j] = (short)f2bf(p[tt * 8 + j] * inv);
            *(bf16x8*)&Sb[row][col] = pb;
        }
    }
    __syncthreads();

    // ---- P3: PV (+residual).  V tiles staged coalesced, double-buffered. ----
    const int stiles = (qt == 0) ? 16 : ccount;   // row 0 is a full uniform row
    f32x4 acc3 = {};
    const int dloc = w * 16 + lr;                 // 0..127
    const int dcol = kh * 128 + dloc;
    const int vrow = t >> 3, vcol = (t & 7) * 16;
    for (int ti = 0; ti < stiles; ++ti) {
        const int buf = ti & 1;
        const unsigned short* vp = hidb + (size_t)(b * Lc + ti * 64 + vrow) * Dc + kh * 128 + vcol;
        *(bf16x8*)&KV[buf][vrow][vcol]     = *(const bf16x8*)vp;
        *(bf16x8*)&KV[buf][vrow][vcol + 8] = *(const bf16x8*)(vp + 8);
        __syncthreads();
        #pragma unroll
        for (int ks = 0; ks < 2; ++ks) {
            bf16x8 pa = *(const bf16x8*)&Sb[lr][ti * 64 + ks * 32 + lg * 8];
            bf16x8 bb;
            #pragma unroll
            for (int j = 0; j < 8; ++j)
                bb[j] = (short)KV[buf][ks * 32 + lg * 8 + j][dloc];
            acc3 = __builtin_amdgcn_mfma_f32_16x16x32_bf16(pa, bb, acc3, 0, 0, 0);
        }
    }

    #pragma unroll
    for (int r = 0; r < 4; ++r) {
        const size_t idx = (size_t)(b * Lc + q0 + lg * 4 + r) * Dc + dcol;
        const float v = res[idx] + acc3[r];
        outp[idx] = v;
        if (hidnext) hidnext[idx] = f2bf(v);
    }
}

// ---------------------------------------------------------------------------
extern "C" void kernel_launch(void* const* d_in, const int* in_sizes, int n_in,
                              void* d_out, int out_size, void* d_ws, size_t ws_size,
                              hipStream_t stream)
{
    const float* x  = (const float*)d_in[0];
    const float* Wq = (const float*)d_in[1];
    const float* bq = (const float*)d_in[2];
    const float* Wk = (const float*)d_in[3];
    const float* bk = (const float*)d_in[4];
    float* out = (float*)d_out;

    unsigned short* hidbA = (unsigned short*)d_ws;             // [4096][1024] bf16 (8 MB)
    unsigned short* hidbB = hidbA + (size_t)Bc * Lc * Dc;      // [4096][1024] bf16 (8 MB)
    unsigned short* qb    = hidbB + (size_t)Bc * Lc * Dc;      // [4096][512]  bf16 (4 MB)
    unsigned short* kb    = qb    + (size_t)Bc * Lc * NHc;     // [4096][512]  bf16 (4 MB)

    const int nhid = Bc * Lc * Dc;   // 4194304

    cast_bf16<<<nhid / 8 / 256, 256, 0, stream>>>(x, hidbA, nhid);
    wtrans<<<dim3(16, 8, 4), 256, 0, stream>>>(Wq, Wk, out);

    for (int l = 0; l < 2; ++l) {
        float* attL = out + (size_t)l * (GSZ / 2);
        float* outL = out + GSZ + (size_t)l * OSZ;
        const float* resL = l ? (out + GSZ) : x;
        const unsigned short* hidL = l ? hidbB : hidbA;
        const unsigned short* WtL = (const unsigned short*)attL;

        qk_gemm<<<dim3(32, 4, 2), 512, 0, stream>>>(
            hidL, WtL, WtL + (size_t)NHc * Dc, bq + l * NHc, bk + l * NHc, qb, kb);

        attn_fused<<<Bc * 64 * Kc, 512, 0, stream>>>(
            qb, kb, hidL, resL, attL, outL, l == 0 ? hidbB : (unsigned short*)nullptr);
    }
}